// Round 1
// baseline (128.199 us; speedup 1.0000x reference)
//
#include <hip/hip_runtime.h>

// Top1Gate: logits = x @ W^T  [16384, 64]; idx = argmax; scores = max; mask = one-hot.
// Output flat layout (float32): [idx as float 16384][scores 16384][mask 16384*64]

constexpr int BATCH = 16384;
constexpr int DM    = 2048;
constexpr int NE    = 64;
constexpr int BM    = 64;    // rows per block
constexpr int KB    = 64;    // K chunk staged in LDS
constexpr int NT    = 512;   // threads per block (8 waves)

__global__ __launch_bounds__(NT, 1)
void top1gate_kernel(const float* __restrict__ x,
                     const float* __restrict__ w,
                     float* __restrict__ out)
{
    __shared__ float xs[BM][KB + 1];     // +1 pad: stride 65 -> conflict-free
    __shared__ float ws[NE][KB + 1];
    __shared__ float lg[BM][NE + 1];
    __shared__ float s_score[BM];
    __shared__ int   s_idx[BM];

    const int t    = threadIdx.x;
    const int row0 = blockIdx.x * BM;

    const int tr = t >> 5;   // 0..15 -> rows tr*4 .. tr*4+3
    const int tc = t & 31;   // experts tc*2, tc*2+1

    float acc[4][2];
    #pragma unroll
    for (int i = 0; i < 4; ++i) { acc[i][0] = 0.f; acc[i][1] = 0.f; }

    for (int k0 = 0; k0 < DM; k0 += KB) {
        __syncthreads();   // protect LDS from previous chunk's readers
        // stage x chunk: BM x KB = 4096 floats = 1024 float4; 2 per thread
        #pragma unroll
        for (int l = 0; l < 2; ++l) {
            int idx = l * NT + t;            // 0..1023
            int r   = idx >> 4;              // 16 float4 per row
            int c   = (idx & 15) << 2;
            float4 v = *reinterpret_cast<const float4*>(
                x + (size_t)(row0 + r) * DM + k0 + c);
            xs[r][c+0] = v.x; xs[r][c+1] = v.y; xs[r][c+2] = v.z; xs[r][c+3] = v.w;
        }
        // stage w chunk: NE x KB
        #pragma unroll
        for (int l = 0; l < 2; ++l) {
            int idx = l * NT + t;
            int r   = idx >> 4;
            int c   = (idx & 15) << 2;
            float4 v = *reinterpret_cast<const float4*>(
                w + (size_t)r * DM + k0 + c);
            ws[r][c+0] = v.x; ws[r][c+1] = v.y; ws[r][c+2] = v.z; ws[r][c+3] = v.w;
        }
        __syncthreads();

        #pragma unroll 8
        for (int kk = 0; kk < KB; ++kk) {
            float b0 = ws[tc*2+0][kk];
            float b1 = ws[tc*2+1][kk];
            #pragma unroll
            for (int i = 0; i < 4; ++i) {
                float a = xs[tr*4+i][kk];
                acc[i][0] = fmaf(a, b0, acc[i][0]);
                acc[i][1] = fmaf(a, b1, acc[i][1]);
            }
        }
    }

    // dump logits to LDS
    #pragma unroll
    for (int i = 0; i < 4; ++i) {
        lg[tr*4+i][tc*2+0] = acc[i][0];
        lg[tr*4+i][tc*2+1] = acc[i][1];
    }
    __syncthreads();

    // per-row argmax (first occurrence wins, matching jnp.argmax)
    if (t < BM) {
        float m  = lg[t][0];
        int   mi = 0;
        #pragma unroll
        for (int e = 1; e < NE; ++e) {
            float v = lg[t][e];
            if (v > m) { m = v; mi = e; }
        }
        s_score[t] = m;
        s_idx[t]   = mi;
        out[row0 + t]         = (float)mi;  // idx as float32
        out[BATCH + row0 + t] = m;          // scores
    }
    __syncthreads();

    // one-hot mask: 64 rows x 64 experts = 4096 floats; 8 per thread, coalesced
    float* mask = out + 2 * BATCH;
    #pragma unroll
    for (int l = 0; l < 8; ++l) {
        int idx = l * NT + t;    // 0..4095
        int r   = idx >> 6;
        int e   = idx & 63;
        mask[(size_t)(row0 + r) * NE + e] = (e == s_idx[r]) ? 1.0f : 0.0f;
    }
}

extern "C" void kernel_launch(void* const* d_in, const int* in_sizes, int n_in,
                              void* d_out, int out_size, void* d_ws, size_t ws_size,
                              hipStream_t stream) {
    const float* x = (const float*)d_in[0];
    const float* w = (const float*)d_in[1];
    float* out     = (float*)d_out;

    dim3 grid(BATCH / BM);   // 256 blocks
    dim3 block(NT);
    top1gate_kernel<<<grid, block, 0, stream>>>(x, w, out);
}

// Round 2
// 54.163 us; speedup vs baseline: 2.3669x; 2.3669x over previous
//
#include <hip/hip_runtime.h>

// Top1Gate via bf16x3-split MFMA GEMM.
// logits = x @ W^T  [16384, 64]; idx = argmax; scores = max; mask = one-hot.
// Output flat (float32): [idx 16384][scores 16384][mask 16384*64]

typedef float  f32x4  __attribute__((ext_vector_type(4)));
typedef short  bf16x8 __attribute__((ext_vector_type(8)));

constexpr int BATCH = 16384;
constexpr int DM    = 2048;
constexpr int NE    = 64;
constexpr int BM    = 64;           // rows per block
constexpr int KB    = 64;           // K per staged chunk
constexpr int NT    = 256;          // 4 waves
constexpr int NCH   = DM / KB;      // 32 chunks
constexpr int KSTEPS= KB / 32;      // 2 mfma k-steps per chunk

// w fragment store (in d_ws), bf16 as ushort:
// [ks=64][term=2(hi,lo)][tile=4][lane=64][j=8]  -> 524288 B total
// value = w_term[expert = tile*16 + (lane&15)][k = ks*32 + (lane>>4)*8 + j]

__device__ __forceinline__ void split_bf16(float f, unsigned short& hi, unsigned short& lo) {
    unsigned u  = __float_as_uint(f);
    unsigned h  = (u + 0x8000u) >> 16;           // round-half-up to bf16
    float    hf = __uint_as_float(h << 16);
    unsigned l  = __float_as_uint(f - hf) >> 16; // truncate residual
    hi = (unsigned short)h;
    lo = (unsigned short)l;
}

__global__ __launch_bounds__(256, 1)
void wconv_kernel(const float* __restrict__ w, unsigned short* __restrict__ wf) {
    int i  = blockIdx.x * 256 + threadIdx.x;     // 0..131071
    int ks = i >> 11;
    int n  = (i >> 9) & 3;
    int l  = (i >> 3) & 63;
    int j  = i & 7;
    int e  = n * 16 + (l & 15);
    int k  = ks * 32 + (l >> 4) * 8 + j;
    float v = w[(size_t)e * DM + k];
    unsigned short hi, lo;
    split_bf16(v, hi, lo);
    int base = ((ks * 2 + 0) * 4 + n) * 512 + l * 8 + j;
    wf[base]        = hi;               // term 0
    wf[base + 2048] = lo;               // term 1 (+4 tiles * 512)
}

__global__ __launch_bounds__(NT, 1)
void gate_kernel(const float* __restrict__ x,
                 const unsigned short* __restrict__ wf,
                 float* __restrict__ out) {
    __shared__ float          xs[3][BM * KB];                  // 3 x 16 KB, swizzled f4 slots
    __shared__ unsigned short wsh[3][KSTEPS * 2 * 4 * 64 * 8]; // 3 x 16 KB, fragment-major
    __shared__ float          lg[BM][NE + 1];
    __shared__ int            s_idx[BM];

    const int t    = threadIdx.x;
    const int lane = t & 63;
    const int wv   = t >> 6;
    const int row0 = blockIdx.x * BM;

    f32x4 acc[4];
    #pragma unroll
    for (int n = 0; n < 4; ++n) acc[n] = (f32x4){0.f, 0.f, 0.f, 0.f};

    auto stage = [&](int c, int b) {
        // x chunk: 64 rows x 64 k fp32 = 1024 float4; slot (r,s) <- global f4 (r, s^(r&7))
        const float* xg = x + (size_t)row0 * DM + c * KB;
        #pragma unroll
        for (int i = 0; i < 4; ++i) {
            int d    = i * NT + t;        // 0..1023 linear dest f4 index
            int r    = d >> 4;
            int sdst = d & 15;
            int ssrc = sdst ^ (r & 7);
            const float* gp = xg + (size_t)r * DM + ssrc * 4;
            __builtin_amdgcn_global_load_lds(
                (__attribute__((address_space(1))) void*)gp,
                (__attribute__((address_space(3))) void*)(&xs[b][d * 4]),
                16, 0, 0);
        }
        // w chunk: 16 KB contiguous fragment-major
        const unsigned short* wg = wf + (size_t)c * 8192;
        #pragma unroll
        for (int i = 0; i < 4; ++i) {
            int d = i * NT + t;           // 0..1023
            __builtin_amdgcn_global_load_lds(
                (__attribute__((address_space(1))) void*)(wg + d * 8),
                (__attribute__((address_space(3))) void*)(&wsh[b][d * 8]),
                16, 0, 0);
        }
    };

    auto compute = [&](int b) {
        const int rA   = wv * 16 + (lane & 15);
        const int kgrp = lane >> 4;
        #pragma unroll
        for (int ksl = 0; ksl < KSTEPS; ++ksl) {
            int fs0 = ksl * 8 + kgrp * 2;
            f32x4 a0 = *(const f32x4*)&xs[b][(rA * 16 + ((fs0 + 0) ^ (rA & 7))) * 4];
            f32x4 a1 = *(const f32x4*)&xs[b][(rA * 16 + ((fs0 + 1) ^ (rA & 7))) * 4];
            bf16x8 ahi, alo;
            #pragma unroll
            for (int j = 0; j < 8; ++j) {
                float f = (j < 4) ? a0[j] : a1[j - 4];
                unsigned short h, l;
                split_bf16(f, h, l);
                ahi[j] = (short)h;
                alo[j] = (short)l;
            }
            #pragma unroll
            for (int n = 0; n < 4; ++n) {
                bf16x8 bhi = *(const bf16x8*)&wsh[b][((ksl * 2 + 0) * 4 + n) * 512 + lane * 8];
                bf16x8 blo = *(const bf16x8*)&wsh[b][((ksl * 2 + 1) * 4 + n) * 512 + lane * 8];
                acc[n] = __builtin_amdgcn_mfma_f32_16x16x32_bf16(ahi, bhi, acc[n], 0, 0, 0);
                acc[n] = __builtin_amdgcn_mfma_f32_16x16x32_bf16(ahi, blo, acc[n], 0, 0, 0);
                acc[n] = __builtin_amdgcn_mfma_f32_16x16x32_bf16(alo, bhi, acc[n], 0, 0, 0);
            }
        }
    };

    // prologue: 2 chunks in flight, wait for chunk 0
    stage(0, 0);
    stage(1, 1);
    asm volatile("s_waitcnt vmcnt(8)" ::: "memory");
    __builtin_amdgcn_sched_barrier(0);
    __builtin_amdgcn_s_barrier();

    #pragma unroll 1
    for (int c = 0; c < NCH; ++c) {
        if (c + 2 < NCH) stage(c + 2, (c + 2) % 3);
        compute(c % 3);
        if (c + 2 < NCH) {
            asm volatile("s_waitcnt vmcnt(8)" ::: "memory");   // chunk c+1 landed, c+2 in flight
        } else if (c + 1 < NCH) {
            asm volatile("s_waitcnt vmcnt(0)" ::: "memory");   // tail: drain last chunk
        }
        __builtin_amdgcn_sched_barrier(0);
        __builtin_amdgcn_s_barrier();
    }

    // epilogue: logits -> LDS  (C/D layout: col=lane&15, row=(lane>>4)*4+q)
    #pragma unroll
    for (int n = 0; n < 4; ++n)
        #pragma unroll
        for (int q = 0; q < 4; ++q)
            lg[wv * 16 + (lane >> 4) * 4 + q][n * 16 + (lane & 15)] = acc[n][q];
    __syncthreads();

    if (t < BM) {
        float m  = lg[t][0];
        int   mi = 0;
        #pragma unroll
        for (int e = 1; e < NE; ++e) {
            float v = lg[t][e];
            if (v > m) { m = v; mi = e; }
        }
        s_idx[t] = mi;
        out[row0 + t]         = (float)mi;
        out[BATCH + row0 + t] = m;
    }
    __syncthreads();

    float* mask = out + 2 * (size_t)BATCH;
    int r  = t >> 2;
    int c0 = (t & 3) * 16;
    int mi = s_idx[r];
    #pragma unroll
    for (int i = 0; i < 4; ++i) {
        f32x4 v;
        #pragma unroll
        for (int j = 0; j < 4; ++j) v[j] = (c0 + i * 4 + j == mi) ? 1.0f : 0.0f;
        *(f32x4*)&mask[(size_t)(row0 + r) * NE + c0 + i * 4] = v;
    }
}

extern "C" void kernel_launch(void* const* d_in, const int* in_sizes, int n_in,
                              void* d_out, int out_size, void* d_ws, size_t ws_size,
                              hipStream_t stream) {
    const float* x = (const float*)d_in[0];
    const float* w = (const float*)d_in[1];
    float* out     = (float*)d_out;
    unsigned short* wf = (unsigned short*)d_ws;   // needs 512 KB

    wconv_kernel<<<dim3(512), dim3(256), 0, stream>>>(w, wf);
    gate_kernel<<<dim3(BATCH / BM), dim3(NT), 0, stream>>>(x, wf, out);
}

// Round 3
// 49.237 us; speedup vs baseline: 2.6037x; 1.1001x over previous
//
#include <hip/hip_runtime.h>

// Top1Gate via bf16x3-split MFMA GEMM, v3.
// logits = x @ W^T [16384,64]; idx = argmax; scores = max; mask = one-hot.
// Output flat (float32): [idx 16384][scores 16384][mask 16384*64]
//
// v3: BM=32, 512 blocks (2/CU, 2 waves/SIMD, decoupled barriers).
//     W fragments in double-buffered registers (L2-hot), only x staged in LDS
//     (3-deep, XOR-swizzled global_load_lds). K split across wave pairs.

typedef float  f32x4  __attribute__((ext_vector_type(4)));
typedef short  bf16x8 __attribute__((ext_vector_type(8)));

constexpr int BATCH = 16384;
constexpr int DM    = 2048;
constexpr int NE    = 64;
constexpr int BM    = 32;          // rows per block
constexpr int KB    = 64;          // K per staged chunk
constexpr int NT    = 256;         // 4 waves: 2 row-tiles x 2 k-halves
constexpr int NCH   = DM / KB;     // 32 chunks

// wf layout (d_ws, ushort): [ks=64][term=2][tile=4][lane=64][j=8]
// value = w_term[expert = tile*16 + (lane&15)][k = ks*32 + (lane>>4)*8 + j]

__device__ __forceinline__ void split_bf16(float f, unsigned short& hi, unsigned short& lo) {
    unsigned u  = __float_as_uint(f);
    unsigned h  = (u + 0x8000u) >> 16;           // round-half-up to bf16
    float    hf = __uint_as_float(h << 16);
    unsigned l  = __float_as_uint(f - hf) >> 16; // truncate residual
    hi = (unsigned short)h;
    lo = (unsigned short)l;
}

__global__ __launch_bounds__(256, 1)
void wconv_kernel(const float* __restrict__ w, unsigned short* __restrict__ wf) {
    int i  = blockIdx.x * 256 + threadIdx.x;     // 0..131071
    int ks = i >> 11;
    int n  = (i >> 9) & 3;
    int l  = (i >> 3) & 63;
    int j  = i & 7;
    int e  = n * 16 + (l & 15);
    int k  = ks * 32 + (l >> 4) * 8 + j;
    float v = w[(size_t)e * DM + k];
    unsigned short hi, lo;
    split_bf16(v, hi, lo);
    int base = ((ks * 2 + 0) * 4 + n) * 512 + l * 8 + j;
    wf[base]        = hi;               // term 0
    wf[base + 2048] = lo;               // term 1
}

struct BSet { bf16x8 v[8]; };   // [term=2][tile=4]

__global__ __launch_bounds__(NT, 2)
void gate_kernel(const float* __restrict__ x,
                 const unsigned short* __restrict__ wf,
                 float* __restrict__ out) {
    __shared__ alignas(16) float xs[3][BM * KB];   // 3 x 8 KB, swizzled f4 slots
    __shared__ float lg[BM][NE + 1];               // stride 65: conflict-free scan
    __shared__ int   s_idx[BM];

    const int t    = threadIdx.x;
    const int lane = t & 63;
    const int wv   = t >> 6;
    const int rt   = wv >> 1;      // row-tile 0/1
    const int kh   = wv & 1;       // k-half 0/1
    const int row0 = blockIdx.x * BM;

    f32x4 acc[4];
    #pragma unroll
    for (int n = 0; n < 4; ++n) acc[n] = (f32x4){0.f, 0.f, 0.f, 0.f};

    // stage x chunk c into buffer b: 32 rows x 64 k fp32 = 512 f4, 2/thread
    auto stage_x = [&](int c, int b) {
        const float* xg = x + (size_t)row0 * DM + c * KB;
        #pragma unroll
        for (int i = 0; i < 2; ++i) {
            int d    = i * NT + t;       // 0..511 linear dest f4 slot
            int r    = d >> 4;
            int sdst = d & 15;
            int ssrc = sdst ^ (r & 7);   // pre-swizzled source (linear LDS dest)
            __builtin_amdgcn_global_load_lds(
                (const __attribute__((address_space(1))) void*)(xg + (size_t)r * DM + ssrc * 4),
                (__attribute__((address_space(3))) void*)(&xs[b][d * 4]),
                16, 0, 0);
        }
    };

    // load this wave's B fragments for chunk c (k-step = kh) into registers
    auto load_b = [&](int c, BSet& B) {
        int ks = c * 2 + kh;
        const unsigned short* wg = wf + (size_t)(ks * 8) * 512 + lane * 8;
        #pragma unroll
        for (int f = 0; f < 8; ++f)           // f = term*4 + tile
            B.v[f] = *(const bf16x8*)(wg + (size_t)f * 512);
    };

    auto compute = [&](int b, const BSet& B) {
        const int rA  = rt * 16 + (lane & 15);
        const int fs0 = kh * 8 + (lane >> 4) * 2;
        f32x4 a0 = *(const f32x4*)&xs[b][(rA * 16 + ((fs0 + 0) ^ (rA & 7))) * 4];
        f32x4 a1 = *(const f32x4*)&xs[b][(rA * 16 + ((fs0 + 1) ^ (rA & 7))) * 4];
        bf16x8 ahi, alo;
        #pragma unroll
        for (int j = 0; j < 8; ++j) {
            float f = (j < 4) ? a0[j] : a1[j - 4];
            unsigned short h, l;
            split_bf16(f, h, l);
            ahi[j] = (short)h;
            alo[j] = (short)l;
        }
        #pragma unroll
        for (int n = 0; n < 4; ++n) {
            acc[n] = __builtin_amdgcn_mfma_f32_16x16x32_bf16(ahi, B.v[0 + n], acc[n], 0, 0, 0);
            acc[n] = __builtin_amdgcn_mfma_f32_16x16x32_bf16(ahi, B.v[4 + n], acc[n], 0, 0, 0);
            acc[n] = __builtin_amdgcn_mfma_f32_16x16x32_bf16(alo, B.v[0 + n], acc[n], 0, 0, 0);
        }
    };

    BSet BA, BB;

    // prologue: x(0),x(1) staged; B(0) in regs. outstanding: x0:2,B0:8,x1:2
    stage_x(0, 0);
    load_b(0, BA);
    stage_x(1, 1);
    asm volatile("s_waitcnt vmcnt(10)" ::: "memory");   // x(0) landed
    __builtin_amdgcn_sched_barrier(0);
    __builtin_amdgcn_s_barrier();

    #pragma unroll 1
    for (int c = 0; c < 30; c += 2) {
        // iter c: uses xs[c%3], BA=B(c)
        stage_x(c + 2, (c + 2) % 3);
        load_b(c + 1, BB);
        compute(c % 3, BA);
        asm volatile("s_waitcnt vmcnt(10)" ::: "memory");  // x(c+1) landed; x(c+2),B(c+1) in flight
        __builtin_amdgcn_sched_barrier(0);
        __builtin_amdgcn_s_barrier();
        // iter c+1: uses xs[(c+1)%3], BB=B(c+1)
        stage_x(c + 3, (c + 3) % 3);
        load_b(c + 2, BA);
        compute((c + 1) % 3, BB);
        asm volatile("s_waitcnt vmcnt(10)" ::: "memory");  // x(c+2) landed
        __builtin_amdgcn_sched_barrier(0);
        __builtin_amdgcn_s_barrier();
    }
    // iter 30: BA=B(30)
    load_b(31, BB);
    compute(30 % 3, BA);
    asm volatile("s_waitcnt vmcnt(8)" ::: "memory");       // x(31) landed; B(31) in flight
    __builtin_amdgcn_sched_barrier(0);
    __builtin_amdgcn_s_barrier();
    // iter 31: BB=B(31)
    compute(31 % 3, BB);
    __syncthreads();

    // k-reduce across wave pairs + logits to LDS
    // C/D layout: row_local = (lane>>4)*4+q, col = n*16 + (lane&15)
    const int rloc = rt * 16 + ((lane >> 4) << 2);
    const int cb   = lane & 15;
    if (kh == 1) {
        #pragma unroll
        for (int n = 0; n < 4; ++n)
            #pragma unroll
            for (int q = 0; q < 4; ++q)
                lg[rloc + q][n * 16 + cb] = acc[n][q];
    }
    __syncthreads();
    if (kh == 0) {
        #pragma unroll
        for (int n = 0; n < 4; ++n)
            #pragma unroll
            for (int q = 0; q < 4; ++q)
                lg[rloc + q][n * 16 + cb] += acc[n][q];
    }
    __syncthreads();

    if (t < BM) {
        float m  = lg[t][0];
        int   mi = 0;
        #pragma unroll
        for (int e = 1; e < NE; ++e) {
            float v = lg[t][e];
            if (v > m) { m = v; mi = e; }
        }
        s_idx[t] = mi;
        out[row0 + t]         = (float)mi;
        out[BATCH + row0 + t] = m;
    }
    __syncthreads();

    // one-hot mask: 32 rows x 64 = 2048 floats; 8/thread, coalesced f32x4
    float* mask = out + 2 * (size_t)BATCH;
    int r  = t >> 3;
    int c0 = (t & 7) * 8;
    int mi = s_idx[r];
    #pragma unroll
    for (int i = 0; i < 2; ++i) {
        f32x4 v;
        #pragma unroll
        for (int j = 0; j < 4; ++j) v[j] = (c0 + i * 4 + j == mi) ? 1.0f : 0.0f;
        *(f32x4*)&mask[(size_t)(row0 + r) * NE + c0 + i * 4] = v;
    }
}

extern "C" void kernel_launch(void* const* d_in, const int* in_sizes, int n_in,
                              void* d_out, int out_size, void* d_ws, size_t ws_size,
                              hipStream_t stream) {
    const float* x = (const float*)d_in[0];
    const float* w = (const float*)d_in[1];
    float* out     = (float*)d_out;
    unsigned short* wf = (unsigned short*)d_ws;   // 512 KB

    wconv_kernel<<<dim3(512), dim3(256), 0, stream>>>(w, wf);
    gate_kernel<<<dim3(BATCH / BM), dim3(NT), 0, stream>>>(x, wf, out);
}